// Round 7
// baseline (212.124 us; speedup 1.0000x reference)
//
#include <hip/hip_runtime.h>
#include <hip/hip_bf16.h>

#define T_TOK 2048
#define DM 1024
#define DH 2048
#define NE 8
#define MT_MAX 40   // max live (expert, m-tile) pairs: 4096/128 + 8

using bf16x8 = __attribute__((ext_vector_type(8))) short;
using f32x4  = __attribute__((ext_vector_type(4))) float;

__device__ __forceinline__ unsigned short f2bf(float f) {
  union { float f; unsigned u; } v; v.f = f;
  unsigned r = v.u + 0x7FFFu + ((v.u >> 16) & 1u);
  return (unsigned short)(r >> 16);
}
__device__ __forceinline__ unsigned pk2(float a, float b) {
  return (unsigned)f2bf(a) | ((unsigned)f2bf(b) << 16);
}

// B-tile LDS slot swizzle (writer and reader MUST match)
#define SW(n) ((((n) & 7)) ^ (((n) >> 3) & 7))

// async global->LDS, 16B per lane; dest wave-uniform base (lane*16 implicit)
#define GLOAD16(gsrc, ldst)                                                        \
  __builtin_amdgcn_global_load_lds(                                                \
      (const __attribute__((address_space(1))) unsigned int*)(gsrc),               \
      (__attribute__((address_space(3))) unsigned int*)(ldst), 16, 0, 0)

// ---------------- init: zero per-expert counters ----------------
__global__ void k_init(int* __restrict__ cnt) {
  if (threadIdx.x < NE) cnt[threadIdx.x] = 0;
}

// ---------------- router: 4 tokens/block, f32 softmax, top-2, compaction ----
__global__ __launch_bounds__(256) void k_router(
    const float* __restrict__ x, const float* __restrict__ Wr, const float* __restrict__ br,
    int* __restrict__ cnt, int* __restrict__ idx, float* __restrict__ wgt,
    int* __restrict__ t2r, float* __restrict__ probs, unsigned short* __restrict__ xb)
{
  const int wave = threadIdx.x >> 6, l = threadIdx.x & 63;
  const int t = blockIdx.x * 4 + wave;
  float xv[16];
#pragma unroll
  for (int i = 0; i < 16; ++i) xv[i] = x[t*DM + l + 64*i];
#pragma unroll
  for (int i = 0; i < 16; ++i) xb[t*DM + l + 64*i] = f2bf(xv[i]);

  float acc[8] = {0.f,0.f,0.f,0.f,0.f,0.f,0.f,0.f};
#pragma unroll
  for (int i = 0; i < 16; ++i) {
    const float4* wp = (const float4*)&Wr[(size_t)(l + 64*i)*NE];
    float4 wa = wp[0], wb = wp[1];
    acc[0] += xv[i]*wa.x; acc[1] += xv[i]*wa.y; acc[2] += xv[i]*wa.z; acc[3] += xv[i]*wa.w;
    acc[4] += xv[i]*wb.x; acc[5] += xv[i]*wb.y; acc[6] += xv[i]*wb.z; acc[7] += xv[i]*wb.w;
  }
#pragma unroll
  for (int e = 0; e < 8; ++e) {
#pragma unroll
    for (int off = 32; off; off >>= 1) acc[e] += __shfl_xor(acc[e], off, 64);
    acc[e] += br[e];
  }
  float mx = acc[0];
#pragma unroll
  for (int e = 1; e < 8; ++e) mx = fmaxf(mx, acc[e]);
  float p[8], s = 0.f;
#pragma unroll
  for (int e = 0; e < 8; ++e) { p[e] = expf(acc[e] - mx); s += p[e]; }
  float inv = 1.f / s;
#pragma unroll
  for (int e = 0; e < 8; ++e) p[e] *= inv;

  // top-2, strict > so lowest index wins ties (matches jax.lax.top_k)
  int e0 = 0; float p0 = p[0];
#pragma unroll
  for (int e = 1; e < 8; ++e) if (p[e] > p0) { p0 = p[e]; e0 = e; }
  int e1 = -1; float p1 = -1.f;
#pragma unroll
  for (int e = 0; e < 8; ++e) { if (e == e0) continue; if (p[e] > p1) { p1 = p[e]; e1 = e; } }

  if (l == 0) {
#pragma unroll
    for (int e = 0; e < 8; ++e) probs[t*NE + e] = p[e];
    int pos0 = atomicAdd(&cnt[e0], 1);
    idx[e0*T_TOK + pos0] = t; wgt[e0*T_TOK + pos0] = p0;
    t2r[t*2 + 0] = e0*T_TOK + pos0;
    int pos1 = atomicAdd(&cnt[e1], 1);
    idx[e1*T_TOK + pos1] = t; wgt[e1*T_TOK + pos1] = p1;
    t2r[t*2 + 1] = e1*T_TOK + pos1;
  }
}

// ------ finalize: row_base prefix + lb_loss + compact work table ------------
__global__ __launch_bounds__(256) void k_finalize(
    const int* __restrict__ cnt, int* __restrict__ rb,
    const float* __restrict__ probs, float* __restrict__ out,
    int* __restrict__ MTp, int* __restrict__ mtab)
{
  __shared__ float red[8][256];
  const int tid = threadIdx.x;
  float s[8] = {0.f,0.f,0.f,0.f,0.f,0.f,0.f,0.f};
  for (int t = tid; t < T_TOK; t += 256) {
#pragma unroll
    for (int e = 0; e < 8; ++e) s[e] += probs[t*NE + e];
  }
#pragma unroll
  for (int e = 0; e < 8; ++e) red[e][tid] = s[e];
  __syncthreads();
  for (int w = 128; w > 0; w >>= 1) {
    if (tid < w) {
#pragma unroll
      for (int e = 0; e < 8; ++e) red[e][tid] += red[e][tid + w];
    }
    __syncthreads();
  }
  if (tid == 0) {
    float lb = 0.f;
#pragma unroll
    for (int e = 0; e < 8; ++e) {
      float mean = red[e][0] * (1.f / T_TOK);
      lb += mean * mean;
    }
    out[2097152] = lb * NE;
    int r = 0, mc = 0;
#pragma unroll
    for (int e = 0; e < 8; ++e) {
      rb[e] = r; r += cnt[e];
      int nmt = (cnt[e] + 127) / 128;
      for (int j = 0; j < nmt; ++j) mtab[mc++] = (e << 16) | j;
    }
    *MTp = mc;
  }
}

#define TM1 128
#define TN1 64
#define BKK 64

// ---- FFN1: h,g GEMMs + SwiGLU -> act (bf16). Compact grid; B staged by
// inline f32 reg-transpose-convert straight from W1/W2 (no pre-pass). --------
__global__ __launch_bounds__(256) void k_ffn1b(
    const unsigned short* __restrict__ xb,
    const float* __restrict__ W1, const float* __restrict__ b1,
    const float* __restrict__ W2, const float* __restrict__ b2,
    const int* __restrict__ cnt, const int* __restrict__ rbp,
    const int* __restrict__ idx, unsigned short* __restrict__ act,
    const int* __restrict__ MTp, const int* __restrict__ mtab)
{
  const int mtg = blockIdx.y;
  if (mtg >= *MTp) return;
  const int code = mtab[mtg];
  const int e = code >> 16, mt = code & 0xffff;
  const int Me = cnt[e];
  const int m0 = mt * TM1;
  const int nt = blockIdx.x;
  const int n0 = nt * TN1;

  __shared__ __align__(16) unsigned short As[TM1*BKK];  // 16 KB
  __shared__ __align__(16) unsigned short Bh[TN1*BKK];  // 8 KB
  __shared__ __align__(16) unsigned short Bg[TN1*BKK];  // 8 KB
  __shared__ int toks[TM1];

  const int tid = threadIdx.x;
  if (tid < TM1) toks[tid] = idx[e*T_TOK + min(m0 + tid, Me - 1)];
  __syncthreads();

  const int lane = tid & 63;
  const int wave = tid >> 6;
  const int wm = wave >> 1, wn = wave & 1;
  const int row16 = lane & 15, kg = lane >> 4;
  const int sl = lane & 7;   // A: 16B slot within 128B row
  const int lr = lane >> 3;  // A: row within 8-row wave chunk

  // A stage-source pointers (source swizzle; LDS dest linear) -- unchanged
  const unsigned short* asrc[4];
#pragma unroll
  for (int i = 0; i < 4; ++i) {
    int r = (wave*4 + i)*8 + lr;
    asrc[i] = &xb[(size_t)toks[r]*DM + ((sl ^ (r & 7)) * 8)];
  }

  // B staging role: thread = (k-quad, n-quad) in the 64k x 64n f32 tile
  const int nq = tid & 15;        // n = nq*4 + j
  const int kq = tid >> 4;        // k = kq*4 + i
  const float* w1p = W1 + ((size_t)e*DM + kq*4)*DH + n0 + nq*4;
  const float* w2p = W2 + ((size_t)e*DM + kq*4)*DH + n0 + nq*4;
  const int bunit = kq >> 1, bhalf = (kq & 1) * 8;

  f32x4 ah[4][2], ag[4][2];
#pragma unroll
  for (int i = 0; i < 4; ++i)
#pragma unroll
    for (int j = 0; j < 2; ++j) { ah[i][j] = 0.f; ag[i][j] = 0.f; }

  for (int k0 = 0; k0 < DM; k0 += BKK) {
    // B loads first (vmcnt for cvt waits only on these)
    const float* p1 = w1p + (size_t)k0 * DH;
    const float* p2 = w2p + (size_t)k0 * DH;
    float4 v1[4], v2[4];
#pragma unroll
    for (int i = 0; i < 4; ++i) v1[i] = *(const float4*)(p1 + (size_t)i*DH);
#pragma unroll
    for (int i = 0; i < 4; ++i) v2[i] = *(const float4*)(p2 + (size_t)i*DH);
    // A async stage (drains at barrier)
#pragma unroll
    for (int i = 0; i < 4; ++i)
      GLOAD16(asrc[i] + k0, &As[(wave*4 + i)*512]);
    // register transpose+convert -> swizzled LDS
    const float* f1 = (const float*)v1;
    const float* f2 = (const float*)v2;
#pragma unroll
    for (int j = 0; j < 4; ++j) {
      const int n = nq*4 + j;
      const int bo = n*128 + ((bunit ^ SW(n)) * 16) + bhalf;
      uint2 w1v, w2v;
      w1v.x = pk2(f1[0*4+j], f1[1*4+j]); w1v.y = pk2(f1[2*4+j], f1[3*4+j]);
      w2v.x = pk2(f2[0*4+j], f2[1*4+j]); w2v.y = pk2(f2[2*4+j], f2[3*4+j]);
      *(uint2*)((char*)Bh + bo) = w1v;
      *(uint2*)((char*)Bg + bo) = w2v;
    }
    __syncthreads();
#pragma unroll
    for (int ks = 0; ks < 2; ++ks) {
      const int kslot = ks*4 + kg;
      bf16x8 a[4], vbh[2], vbg[2];
#pragma unroll
      for (int mi = 0; mi < 4; ++mi) {
        int m = wm*64 + mi*16 + row16;
        a[mi] = *(const bf16x8*)&As[m*BKK + ((kslot ^ (m & 7)) * 8)];
      }
#pragma unroll
      for (int ni = 0; ni < 2; ++ni) {
        int n = wn*32 + ni*16 + row16;
        int off = n*BKK + ((kslot ^ SW(n)) * 8);
        vbh[ni] = *(const bf16x8*)&Bh[off];
        vbg[ni] = *(const bf16x8*)&Bg[off];
      }
#pragma unroll
      for (int mi = 0; mi < 4; ++mi)
#pragma unroll
        for (int ni = 0; ni < 2; ++ni) {
          ah[mi][ni] = __builtin_amdgcn_mfma_f32_16x16x32_bf16(a[mi], vbh[ni], ah[mi][ni], 0, 0, 0);
          ag[mi][ni] = __builtin_amdgcn_mfma_f32_16x16x32_bf16(a[mi], vbg[ni], ag[mi][ni], 0, 0, 0);
        }
    }
    __syncthreads();
  }

  const int rb = rbp[e];
#pragma unroll
  for (int mi = 0; mi < 4; ++mi) {
#pragma unroll
    for (int i = 0; i < 4; ++i) {
      int rloc = wm*64 + mi*16 + (lane >> 4)*4 + i;
      int m = m0 + rloc;
      if (m < Me) {
#pragma unroll
        for (int ni = 0; ni < 2; ++ni) {
          int col = n0 + wn*32 + ni*16 + row16;
          float h = ah[mi][ni][i] + b1[e*DH + col];
          float g = ag[mi][ni][i] + b2[e*DH + col];
          float sg = g / (1.f + __expf(-g));
          act[(size_t)(rb + m)*DH + col] = f2bf(h * sg);
        }
      }
    }
  }
}

// ---- FFN2: act @ Wo -> ys (f32). Compact grid; inline Wo transpose. --------
__global__ __launch_bounds__(256) void k_ffn2b(
    const unsigned short* __restrict__ act,
    const float* __restrict__ Wo, const float* __restrict__ bo,
    const int* __restrict__ cnt, const int* __restrict__ rbp,
    float* __restrict__ ys,
    const int* __restrict__ MTp, const int* __restrict__ mtab)
{
  const int mtg = blockIdx.y;
  if (mtg >= *MTp) return;
  const int code = mtab[mtg];
  const int e = code >> 16, mt = code & 0xffff;
  const int Me = cnt[e];
  const int m0 = mt * TM1;
  const int nt = blockIdx.x;
  const int n0 = nt * TN1;
  const int rb = rbp[e];

  __shared__ __align__(16) unsigned short As[TM1*BKK];  // 16 KB
  __shared__ __align__(16) unsigned short Bs[TN1*BKK];  // 8 KB

  const int tid = threadIdx.x;
  const int lane = tid & 63;
  const int wave = tid >> 6;
  const int wm = wave >> 1, wn = wave & 1;
  const int row16 = lane & 15, kg = lane >> 4;
  const int sl = lane & 7;
  const int lr = lane >> 3;

  const unsigned short* asrc[4];
#pragma unroll
  for (int i = 0; i < 4; ++i) {
    int r = (wave*4 + i)*8 + lr;
    int grow = rb + min(m0 + r, Me - 1);
    asrc[i] = &act[(size_t)grow*DH + ((sl ^ (r & 7)) * 8)];
  }

  const int nq = tid & 15;
  const int kq = tid >> 4;
  const float* wop = Wo + ((size_t)e*DH + kq*4)*DM + n0 + nq*4;
  const int bunit = kq >> 1, bhalf = (kq & 1) * 8;

  f32x4 acc[4][2];
#pragma unroll
  for (int i = 0; i < 4; ++i)
#pragma unroll
    for (int j = 0; j < 2; ++j) acc[i][j] = 0.f;

  for (int k0 = 0; k0 < DH; k0 += BKK) {
    const float* p1 = wop + (size_t)k0 * DM;
    float4 v1[4];
#pragma unroll
    for (int i = 0; i < 4; ++i) v1[i] = *(const float4*)(p1 + (size_t)i*DM);
#pragma unroll
    for (int i = 0; i < 4; ++i)
      GLOAD16(asrc[i] + k0, &As[(wave*4 + i)*512]);
    const float* f1 = (const float*)v1;
#pragma unroll
    for (int j = 0; j < 4; ++j) {
      const int n = nq*4 + j;
      const int bo = n*128 + ((bunit ^ SW(n)) * 16) + bhalf;
      uint2 w1v;
      w1v.x = pk2(f1[0*4+j], f1[1*4+j]); w1v.y = pk2(f1[2*4+j], f1[3*4+j]);
      *(uint2*)((char*)Bs + bo) = w1v;
    }
    __syncthreads();
#pragma unroll
    for (int ks = 0; ks < 2; ++ks) {
      const int kslot = ks*4 + kg;
      bf16x8 a[4], b[2];
#pragma unroll
      for (int mi = 0; mi < 4; ++mi) {
        int m = wm*64 + mi*16 + row16;
        a[mi] = *(const bf16x8*)&As[m*BKK + ((kslot ^ (m & 7)) * 8)];
      }
#pragma unroll
      for (int ni = 0; ni < 2; ++ni) {
        int n = wn*32 + ni*16 + row16;
        b[ni] = *(const bf16x8*)&Bs[n*BKK + ((kslot ^ SW(n)) * 8)];
      }
#pragma unroll
      for (int mi = 0; mi < 4; ++mi)
#pragma unroll
        for (int ni = 0; ni < 2; ++ni)
          acc[mi][ni] = __builtin_amdgcn_mfma_f32_16x16x32_bf16(a[mi], b[ni], acc[mi][ni], 0, 0, 0);
    }
    __syncthreads();
  }

#pragma unroll
  for (int mi = 0; mi < 4; ++mi) {
#pragma unroll
    for (int i = 0; i < 4; ++i) {
      int rloc = wm*64 + mi*16 + (lane >> 4)*4 + i;
      int m = m0 + rloc;
      if (m < Me) {
#pragma unroll
        for (int ni = 0; ni < 2; ++ni) {
          int col = n0 + wn*32 + ni*16 + row16;
          ys[(size_t)(rb + m)*DM + col] = acc[mi][ni][i] + bo[e*DM + col];
        }
      }
    }
  }
}

// ---------------- combine: out[t] = w0*ys[r0] + w1*ys[r1] -------------------
__global__ __launch_bounds__(256) void k_combine(
    const float* __restrict__ ys, const int* __restrict__ t2r,
    const int* __restrict__ rbp, const float* __restrict__ wgt,
    float* __restrict__ out)
{
  const int t = blockIdx.x, tid = threadIdx.x;
  const int c0 = t2r[t*2 + 0], c1 = t2r[t*2 + 1];
  const float w0 = wgt[c0], w1 = wgt[c1];
  const int r0 = rbp[c0 >> 11] + (c0 & 2047);
  const int r1 = rbp[c1 >> 11] + (c1 & 2047);
  const float4* p0 = (const float4*)&ys[(size_t)r0*DM];
  const float4* p1 = (const float4*)&ys[(size_t)r1*DM];
  float4* po = (float4*)&out[(size_t)t*DM];
  float4 a = p0[tid], b = p1[tid];
  float4 r;
  r.x = w0*a.x + w1*b.x; r.y = w0*a.y + w1*b.y;
  r.z = w0*a.z + w1*b.z; r.w = w0*a.w + w1*b.w;
  po[tid] = r;
}

extern "C" void kernel_launch(void* const* d_in, const int* in_sizes, int n_in,
                              void* d_out, int out_size, void* d_ws, size_t ws_size,
                              hipStream_t stream)
{
  const float* x  = (const float*)d_in[0];
  const float* W1 = (const float*)d_in[1];
  const float* b1 = (const float*)d_in[2];
  const float* W2 = (const float*)d_in[3];
  const float* b2 = (const float*)d_in[4];
  const float* Wo = (const float*)d_in[5];
  const float* bo = (const float*)d_in[6];
  const float* Wr = (const float*)d_in[7];
  const float* br = (const float*)d_in[8];
  float* out = (float*)d_out;

  char* ws = (char*)d_ws;
  int*   cnt   = (int*)(ws + 0);           // 8 ints
  int*   rb    = (int*)(ws + 64);          // 8 ints
  int*   MTp   = (int*)(ws + 128);         // 1 int
  int*   mtab  = (int*)(ws + 192);         // <=40 ints
  int*   t2r   = (int*)(ws + 4096);        // 16 KB
  int*   idx   = (int*)(ws + 32*1024);     // 64 KB
  float* wgt   = (float*)(ws + 96*1024);   // 64 KB
  float* probs = (float*)(ws + 160*1024);  // 64 KB
  unsigned short* xb  = (unsigned short*)(ws + 256*1024);          // 4 MB
  unsigned short* act = (unsigned short*)(ws + 5ull*1024*1024);    // 16 MB
  float* ysb = (float*)(ws + 21ull*1024*1024);                     // 16 MB

  k_init<<<1, 64, 0, stream>>>(cnt);
  k_router<<<T_TOK/4, 256, 0, stream>>>(x, Wr, br, cnt, idx, wgt, t2r, probs, xb);
  k_finalize<<<1, 256, 0, stream>>>(cnt, rb, probs, out, MTp, mtab);
  k_ffn1b<<<dim3(DH/TN1, MT_MAX), 256, 0, stream>>>(xb, W1, b1, W2, b2, cnt, rb, idx, act, MTp, mtab);
  k_ffn2b<<<dim3(DM/TN1, MT_MAX), 256, 0, stream>>>(act, Wo, bo, cnt, rb, ysb, MTp, mtab);
  k_combine<<<T_TOK, 256, 0, stream>>>(ysb, t2r, rb, wgt, out);
}